// Round 10
// baseline (71.793 us; speedup 1.0000x reference)
//
#include <hip/hip_runtime.h>

// BahdanauAttnDecoderRNN single-step decode, MI355X — 4 stream-ordered kernels.
// Reference dead code: softmax over size-1 axis => attn_weights == 1.0;
// attn_W/attn_b/scores dead; attn_applied = colsum(encoder_outputs).
// Live work ~178 MB f32 reads (Wout 131 MB dominant) => ~28 us HBM roofline.
// Sync rules (measured): NO intra-kernel polling (R4 441us / R5 486us);
// single-shot last-arrival-wins is safe up to ~256 fan-in (R7 ok at 192,
// R8 BROKE at 2048: 420us + wrong results). Winner test (old&(N-1))==N-1
// with power-of-2 N: immune to ws poison + replay accumulation, no resets.
// R9 lesson: per-block overhead in the logits stream dominated — fewer
// blocks x longer sequential per-wave streams won 13us. Continue that lever:
//   D1: colsum 128x16-row chunks (64KB blocks, balanced with GRU blocks) +
//       gh + emb-half gi + ones; 128th arrival reduces partials -> rn  (~6us)
//   D2: gi2 = Wih[:,H:2H].rn, 192 blocks, no prologue reduce          (~2.5us)
//   D3: gates redundant per block + 64-row logits (16/wave, unroll 4)
//       + per-block (m,s) partial                                     (~23us)
//   D4: fixed-order reduce of 500 partials + in-place log-softmax     (~1.3us)

namespace {
constexpr int H = 1024;
constexpr int V = 32000;
constexpr int S = 2048;
constexpr int NTHR = 256;
constexpr int CS_BLKS = 128;            // colsum chunks (power of 2, safe fan-in)
constexpr int CS_ROWS = S / CS_BLKS;    // 16 rows per chunk
constexpr int GRU_BLKS = 768;           // 3072 rows / 4 per block
constexpr int D1_BLKS = CS_BLKS + GRU_BLKS + 1;  // 897
constexpr int D2_BLKS = 192;            // 16 gi2 rows each
constexpr int D3_BLKS = 500;            // 64 logits rows each (16 per wave)
constexpr int RPW = 16;                 // rows per wave in D3
constexpr int D4_BLKS = V / NTHR;       // 125
}

__device__ __forceinline__ float wave_sum(float v) {
#pragma unroll
    for (int off = 32; off > 0; off >>= 1) v += __shfl_xor(v, off, 64);
    return v;
}
__device__ __forceinline__ float wave_max(float v) {
#pragma unroll
    for (int off = 32; off > 0; off >>= 1) v = fmaxf(v, __shfl_xor(v, off, 64));
    return v;
}
__device__ __forceinline__ float dot4(float4 a, float4 b) {
    return a.x * b.x + a.y * b.y + a.z * b.z + a.w * b.w;
}

// D1: colsum partials (128 chunks; last arrival reduces -> rn=relu(colsum))
// + gh & emb-half of gi + attn ones.
__global__ __launch_bounds__(NTHR) void k_front(
    const float* __restrict__ enc, const float* __restrict__ Whh,
    const float* __restrict__ Wih, const float* __restrict__ bih,
    const float* __restrict__ bhh, const float* __restrict__ hin,
    const float* __restrict__ emb, const int* __restrict__ word,
    float* __restrict__ part, float* __restrict__ rn,
    float* __restrict__ gi, float* __restrict__ gh,
    float* __restrict__ out, int* __restrict__ ctrA) {
    const int b = blockIdx.x, t = threadIdx.x;
    __shared__ int win;
    if (b < CS_BLKS) {
        // rows [b*16, b*16+16); thread t owns float4-column t
        const float4* e = (const float4*)enc + (size_t)b * CS_ROWS * (H / 4) + t;
        float4 acc = make_float4(0.f, 0.f, 0.f, 0.f);
#pragma unroll
        for (int r = 0; r < CS_ROWS; ++r) {
            float4 v = e[(size_t)r * (H / 4)];
            acc.x += v.x; acc.y += v.y; acc.z += v.z; acc.w += v.w;
        }
        ((float4*)part)[b * (H / 4) + t] = acc;
        __threadfence();  // release partials
        __syncthreads();
        if (t == 0) {
            const int old = __hip_atomic_fetch_add(ctrA, 1, __ATOMIC_ACQ_REL,
                                                   __HIP_MEMORY_SCOPE_AGENT);
            win = ((old & (CS_BLKS - 1)) == CS_BLKS - 1);
        }
        __syncthreads();
        if (win) {
            __threadfence();  // acquire: see all partials
            float4 s = make_float4(0.f, 0.f, 0.f, 0.f);
            for (int c = 0; c < CS_BLKS; ++c) {
                float4 v = ((const float4*)part)[c * (H / 4) + t];
                s.x += v.x; s.y += v.y; s.z += v.z; s.w += v.w;
            }
            s.x = fmaxf(s.x, 0.f); s.y = fmaxf(s.y, 0.f);
            s.z = fmaxf(s.z, 0.f); s.w = fmaxf(s.w, 0.f);
            ((float4*)rn)[t] = s;
        }
    } else if (b < CS_BLKS + GRU_BLKS) {
        const int lane = t & 63, w = t >> 6;
        const int row = (b - CS_BLKS) * 4 + w;  // < 3072
        const float4* wh = (const float4*)Whh + (size_t)row * (H / 4);
        const float4* xh = (const float4*)hin;
        const float4* wi = (const float4*)Wih + (size_t)row * (2 * H / 4);
        const float4* er = (const float4*)emb + (size_t)word[0] * (H / 4);
        float ah = 0.f, ai = 0.f;
#pragma unroll
        for (int it = 0; it < 4; ++it) {
            const int idx = it * 64 + lane;
            ah += dot4(wh[idx], xh[idx]);
            float4 e4 = er[idx];
            e4.x = fmaxf(e4.x, 0.f); e4.y = fmaxf(e4.y, 0.f);
            e4.z = fmaxf(e4.z, 0.f); e4.w = fmaxf(e4.w, 0.f);
            ai += dot4(wi[idx], e4);
        }
        ah = wave_sum(ah);
        ai = wave_sum(ai);
        if (lane == 0) {
            gh[row] = ah + bhh[row];
            gi[row] = ai + bih[row];  // colsum half lives in gi2
        }
    } else {
        // attn_weights are exactly 1.0 (softmax over size-1 axis)
#pragma unroll
        for (int k = 0; k < S / NTHR; ++k) out[V + H + k * NTHR + t] = 1.0f;
    }
}

// D2: gi2 = Wih[:, H:2H] . rn (192 blocks x 16 rows); rn read directly (4 KB).
__global__ __launch_bounds__(NTHR) void k_gi2(
    const float* __restrict__ Wih, const float* __restrict__ rn,
    float* __restrict__ gi2) {
    __shared__ float4 sh[H / 4];
    const int t = threadIdx.x, lane = t & 63, w = t >> 6;
    sh[t] = ((const float4*)rn)[t];
    __syncthreads();
#pragma unroll
    for (int i = 0; i < 4; ++i) {
        const int row = blockIdx.x * 16 + w * 4 + i;  // < 3072
        const float4* wr = (const float4*)Wih + (size_t)row * (2 * H / 4) + (H / 4);
        float a = 0.f;
#pragma unroll
        for (int it = 0; it < 4; ++it) {
            const int idx = it * 64 + lane;
            a += dot4(wr[idx], sh[idx]);
        }
        a = wave_sum(a);
        if (lane == 0) gi2[row] = a;
    }
}

// D3: gates redundant per block -> h_new in LDS -> 64-row Wout matvec
// (16 rows/wave, unroll 4) -> raw logits + per-block (m,s) partial.
__global__ __launch_bounds__(NTHR) void k_logits(
    const float* __restrict__ gi, const float* __restrict__ gi2,
    const float* __restrict__ gh, const float* __restrict__ hin,
    const float* __restrict__ Wout, const float* __restrict__ bout,
    float* __restrict__ out, float* __restrict__ partm, float* __restrict__ parts) {
    __shared__ float hnew[H];
    __shared__ float bm[4], bs[4];
    const int t = threadIdx.x, lane = t & 63, w = t >> 6;
#pragma unroll
    for (int q = 0; q < 4; ++q) {
        const int j = q * NTHR + t;
        const float gr = gi[j] + gi2[j] + gh[j];
        const float gz = gi[H + j] + gi2[H + j] + gh[H + j];
        const float r = 1.f / (1.f + expf(-gr));
        const float z = 1.f / (1.f + expf(-gz));
        const float n = tanhf(gi[2 * H + j] + gi2[2 * H + j] + r * gh[2 * H + j]);
        const float hv = (1.f - z) * n + z * hin[j];
        hnew[j] = hv;
        if (blockIdx.x == 0) out[V + j] = hv;  // hidden-state output
    }
    __syncthreads();
    const float4* hn4 = (const float4*)hnew;
    const float4 x0 = hn4[lane], x1 = hn4[64 + lane];
    const float4 x2 = hn4[128 + lane], x3 = hn4[192 + lane];
    float a[RPW];
#pragma unroll 4
    for (int i = 0; i < RPW; ++i) {
        const int row = blockIdx.x * 64 + w * RPW + i;  // < 32000
        const float4* wr = (const float4*)Wout + (size_t)row * (H / 4);
        float v = dot4(wr[lane], x0) + dot4(wr[64 + lane], x1) +
                  dot4(wr[128 + lane], x2) + dot4(wr[192 + lane], x3);
        a[i] = wave_sum(v) + bout[row];  // identical on all lanes
        if (lane == 0) out[row] = a[i];  // raw logit
    }
    float m = a[0];
#pragma unroll
    for (int i = 1; i < RPW; ++i) m = fmaxf(m, a[i]);
    float s = 0.f;
#pragma unroll
    for (int i = 0; i < RPW; ++i) s += expf(a[i] - m);
    if (lane == 0) { bm[w] = m; bs[w] = s; }
    __syncthreads();
    if (t == 0) {
        const float M = fmaxf(fmaxf(bm[0], bm[1]), fmaxf(bm[2], bm[3]));
        const float ss = bs[0] * expf(bm[0] - M) + bs[1] * expf(bm[1] - M) +
                         bs[2] * expf(bm[2] - M) + bs[3] * expf(bm[3] - M);
        partm[blockIdx.x] = M;
        parts[blockIdx.x] = ss;
    }
}

// D4: redundant fixed-order reduce of 500 partials + in-place log-softmax.
__global__ __launch_bounds__(NTHR) void k_final(
    const float* __restrict__ partm, const float* __restrict__ parts,
    float* __restrict__ out) {
    __shared__ float ms[4], ss[4];
    const int t = threadIdx.x, lane = t & 63, w = t >> 6;
    float m = -3.4e38f;
    for (int k = t; k < D3_BLKS; k += NTHR) m = fmaxf(m, partm[k]);
    m = wave_max(m);
    if (lane == 0) ms[w] = m;
    __syncthreads();
    const float M = fmaxf(fmaxf(ms[0], ms[1]), fmaxf(ms[2], ms[3]));
    float s = 0.f;
    for (int k = t; k < D3_BLKS; k += NTHR) s += parts[k] * expf(partm[k] - M);
    s = wave_sum(s);
    if (lane == 0) ss[w] = s;
    __syncthreads();
    const float L = logf(ss[0] + ss[1] + ss[2] + ss[3]);
    const int g = blockIdx.x * NTHR + t;  // 125*256 = 32000
    out[g] = out[g] - M - L;
}

extern "C" void kernel_launch(void* const* d_in, const int* in_sizes, int n_in,
                              void* d_out, int out_size, void* d_ws, size_t ws_size,
                              hipStream_t stream) {
    const int*   word = (const int*)d_in[0];
    const float* hin  = (const float*)d_in[1];
    const float* enc  = (const float*)d_in[2];
    const float* emb  = (const float*)d_in[3];
    // d_in[4] attn_W, d_in[5] attn_b: dead (softmax over size-1 axis)
    const float* Wih  = (const float*)d_in[6];
    const float* Whh  = (const float*)d_in[7];
    const float* bih  = (const float*)d_in[8];
    const float* bhh  = (const float*)d_in[9];
    const float* Wout = (const float*)d_in[10];
    const float* bout = (const float*)d_in[11];
    float* out = (float*)d_out;

    int* ctrA = (int*)d_ws;              // modular winner: no reset needed
    float* ws = (float*)d_ws + 64;
    float* part  = ws;                   // [128*1024]
    float* rn    = part + CS_BLKS * H;   // [1024]
    float* gi    = rn + H;               // [3072]
    float* gi2   = gi + 3 * H;           // [3072]
    float* gh    = gi2 + 3 * H;          // [3072]
    float* partm = gh + 3 * H;           // [500]
    float* parts = partm + D3_BLKS;      // [500]

    k_front<<<D1_BLKS, NTHR, 0, stream>>>(enc, Whh, Wih, bih, bhh, hin, emb, word,
                                          part, rn, gi, gh, out, ctrA);
    k_gi2<<<D2_BLKS, NTHR, 0, stream>>>(Wih, rn, gi2);
    k_logits<<<D3_BLKS, NTHR, 0, stream>>>(gi, gi2, gh, hin, Wout, bout, out,
                                           partm, parts);
    k_final<<<D4_BLKS, NTHR, 0, stream>>>(partm, parts, out);
}

// Round 11
// 59.262 us; speedup vs baseline: 1.2114x; 1.2114x over previous
//
#include <hip/hip_runtime.h>

// BahdanauAttnDecoderRNN single-step decode, MI355X — memset + 4 kernels.
// Reference dead code: softmax over size-1 axis => attn_weights == 1.0;
// attn_W/attn_b/scores dead; attn_applied = colsum(encoder_outputs).
// Live work ~178 MB f32 reads (Wout 131 MB dominant) => ~28 us HBM roofline.
// Measured lessons:
//   - NO intra-kernel polling / grid.sync (R4 441us, R5 486us, R8 420us+wrong).
//   - NO serial winner-reduce on the critical path (R10: one block reducing
//     512 KB cost ~20us; parallel redundant reduce is free by comparison).
//   - Logits stream wants FEW blocks x LONG sequential per-wave streams
//     (R9: 2000x16 -> 1000x32 won 13us; R10's 500x64 regressed, keep 1000x32).
//   - Balance per-block stream lengths inside a dispatch (colsum 256KB blocks
//     were D1's long pole at ~10us vs 36KB GRU blocks).
// Structure (R9 + balanced D1 via R2-proven atomicAdd colsum):
//   D0: memsetAsync colsum[1024] = 0 (4 KB)
//   D1: colsum 128x16-row chunks -> atomicAdd (64KB blocks, balanced)
//       + gh + emb-half gi (768 blocks) + attn ones                    (~6us)
//   D2: rn = relu(colsum) (4 KB read) -> gi2 = Wih[:,H:2H].rn          (~2.5us)
//   D3: gates redundant per block + 32-row logits (8/wave) + (m,s)     (~21us)
//   D4: fixed-order reduce of 1000 partials + in-place log-softmax     (~1.3us)

namespace {
constexpr int H = 1024;
constexpr int V = 32000;
constexpr int S = 2048;
constexpr int NTHR = 256;
constexpr int CS_BLKS = 128;            // colsum chunks (atomicAdd, balanced)
constexpr int CS_ROWS = S / CS_BLKS;    // 16 rows per chunk
constexpr int GRU_BLKS = 768;           // 3072 rows / 4 per block
constexpr int D1_BLKS = CS_BLKS + GRU_BLKS + 1;  // 897
constexpr int D2_BLKS = 192;            // 16 gi2 rows each
constexpr int D3_BLKS = 1000;           // 32 logits rows each (8 per wave)
constexpr int RPW = 8;                  // rows per wave in D3
constexpr int D4_BLKS = V / NTHR;       // 125
}

__device__ __forceinline__ float wave_sum(float v) {
#pragma unroll
    for (int off = 32; off > 0; off >>= 1) v += __shfl_xor(v, off, 64);
    return v;
}
__device__ __forceinline__ float wave_max(float v) {
#pragma unroll
    for (int off = 32; off > 0; off >>= 1) v = fmaxf(v, __shfl_xor(v, off, 64));
    return v;
}
__device__ __forceinline__ float dot4(float4 a, float4 b) {
    return a.x * b.x + a.y * b.y + a.z * b.z + a.w * b.w;
}

// D1: colsum chunks (atomicAdd into zeroed colsum) + gh & emb-half gi + ones.
__global__ __launch_bounds__(NTHR) void k_front(
    const float* __restrict__ enc, const float* __restrict__ Whh,
    const float* __restrict__ Wih, const float* __restrict__ bih,
    const float* __restrict__ bhh, const float* __restrict__ hin,
    const float* __restrict__ emb, const int* __restrict__ word,
    float* __restrict__ colsum, float* __restrict__ gi, float* __restrict__ gh,
    float* __restrict__ out) {
    const int b = blockIdx.x, t = threadIdx.x;
    if (b < CS_BLKS) {
        // rows [b*16, b*16+16); thread t owns float4-column t (cols 4t..4t+3)
        const float4* e = (const float4*)enc + (size_t)b * CS_ROWS * (H / 4) + t;
        float4 acc = make_float4(0.f, 0.f, 0.f, 0.f);
#pragma unroll
        for (int r = 0; r < CS_ROWS; ++r) {
            float4 v = e[(size_t)r * (H / 4)];
            acc.x += v.x; acc.y += v.y; acc.z += v.z; acc.w += v.w;
        }
        atomicAdd(&colsum[t * 4 + 0], acc.x);
        atomicAdd(&colsum[t * 4 + 1], acc.y);
        atomicAdd(&colsum[t * 4 + 2], acc.z);
        atomicAdd(&colsum[t * 4 + 3], acc.w);
    } else if (b < CS_BLKS + GRU_BLKS) {
        const int lane = t & 63, w = t >> 6;
        const int row = (b - CS_BLKS) * 4 + w;  // < 3072
        const float4* wh = (const float4*)Whh + (size_t)row * (H / 4);
        const float4* xh = (const float4*)hin;
        const float4* wi = (const float4*)Wih + (size_t)row * (2 * H / 4);
        const float4* er = (const float4*)emb + (size_t)word[0] * (H / 4);
        float ah = 0.f, ai = 0.f;
#pragma unroll
        for (int it = 0; it < 4; ++it) {
            const int idx = it * 64 + lane;
            ah += dot4(wh[idx], xh[idx]);
            float4 e4 = er[idx];
            e4.x = fmaxf(e4.x, 0.f); e4.y = fmaxf(e4.y, 0.f);
            e4.z = fmaxf(e4.z, 0.f); e4.w = fmaxf(e4.w, 0.f);
            ai += dot4(wi[idx], e4);
        }
        ah = wave_sum(ah);
        ai = wave_sum(ai);
        if (lane == 0) {
            gh[row] = ah + bhh[row];
            gi[row] = ai + bih[row];  // colsum half lives in gi2
        }
    } else {
        // attn_weights are exactly 1.0 (softmax over size-1 axis)
#pragma unroll
        for (int k = 0; k < S / NTHR; ++k) out[V + H + k * NTHR + t] = 1.0f;
    }
}

// D2: rn = relu(colsum) (4 KB direct read) -> LDS; gi2 = Wih[:,H:2H] . rn.
__global__ __launch_bounds__(NTHR) void k_gi2(
    const float* __restrict__ Wih, const float* __restrict__ colsum,
    float* __restrict__ gi2) {
    __shared__ float4 sh[H / 4];
    const int t = threadIdx.x, lane = t & 63, w = t >> 6;
    float4 c = ((const float4*)colsum)[t];
    c.x = fmaxf(c.x, 0.f); c.y = fmaxf(c.y, 0.f);
    c.z = fmaxf(c.z, 0.f); c.w = fmaxf(c.w, 0.f);
    sh[t] = c;
    __syncthreads();
#pragma unroll
    for (int i = 0; i < 4; ++i) {
        const int row = blockIdx.x * 16 + w * 4 + i;  // < 3072
        const float4* wr = (const float4*)Wih + (size_t)row * (2 * H / 4) + (H / 4);
        float a = 0.f;
#pragma unroll
        for (int it = 0; it < 4; ++it) {
            const int idx = it * 64 + lane;
            a += dot4(wr[idx], sh[idx]);
        }
        a = wave_sum(a);
        if (lane == 0) gi2[row] = a;
    }
}

// D3: gates redundant per block -> h_new in LDS -> 32-row Wout matvec
// (8 rows/wave, register batch) -> raw logits + per-block (m,s) partial.
__global__ __launch_bounds__(NTHR) void k_logits(
    const float* __restrict__ gi, const float* __restrict__ gi2,
    const float* __restrict__ gh, const float* __restrict__ hin,
    const float* __restrict__ Wout, const float* __restrict__ bout,
    float* __restrict__ out, float* __restrict__ partm, float* __restrict__ parts) {
    __shared__ float hnew[H];
    __shared__ float bm[4], bs[4];
    const int t = threadIdx.x, lane = t & 63, w = t >> 6;
#pragma unroll
    for (int q = 0; q < 4; ++q) {
        const int j = q * NTHR + t;
        const float gr = gi[j] + gi2[j] + gh[j];
        const float gz = gi[H + j] + gi2[H + j] + gh[H + j];
        const float r = 1.f / (1.f + expf(-gr));
        const float z = 1.f / (1.f + expf(-gz));
        const float n = tanhf(gi[2 * H + j] + gi2[2 * H + j] + r * gh[2 * H + j]);
        const float hv = (1.f - z) * n + z * hin[j];
        hnew[j] = hv;
        if (blockIdx.x == 0) out[V + j] = hv;  // hidden-state output
    }
    __syncthreads();
    const float4* hn4 = (const float4*)hnew;
    const float4 x0 = hn4[lane], x1 = hn4[64 + lane];
    const float4 x2 = hn4[128 + lane], x3 = hn4[192 + lane];
    float a[RPW];
#pragma unroll 2
    for (int i = 0; i < RPW; ++i) {
        const int row = blockIdx.x * 32 + w * RPW + i;  // < 32000
        const float4* wr = (const float4*)Wout + (size_t)row * (H / 4);
        float v = dot4(wr[lane], x0) + dot4(wr[64 + lane], x1) +
                  dot4(wr[128 + lane], x2) + dot4(wr[192 + lane], x3);
        a[i] = wave_sum(v) + bout[row];  // identical on all lanes
        if (lane == 0) out[row] = a[i];  // raw logit
    }
    float m = a[0];
#pragma unroll
    for (int i = 1; i < RPW; ++i) m = fmaxf(m, a[i]);
    float s = 0.f;
#pragma unroll
    for (int i = 0; i < RPW; ++i) s += expf(a[i] - m);
    if (lane == 0) { bm[w] = m; bs[w] = s; }
    __syncthreads();
    if (t == 0) {
        const float M = fmaxf(fmaxf(bm[0], bm[1]), fmaxf(bm[2], bm[3]));
        const float ss = bs[0] * expf(bm[0] - M) + bs[1] * expf(bm[1] - M) +
                         bs[2] * expf(bm[2] - M) + bs[3] * expf(bm[3] - M);
        partm[blockIdx.x] = M;
        parts[blockIdx.x] = ss;
    }
}

// D4: redundant fixed-order reduce of 1000 partials + in-place log-softmax.
__global__ __launch_bounds__(NTHR) void k_final(
    const float* __restrict__ partm, const float* __restrict__ parts,
    float* __restrict__ out) {
    __shared__ float ms[4], ss[4];
    const int t = threadIdx.x, lane = t & 63, w = t >> 6;
    float m = -3.4e38f;
    for (int k = t; k < D3_BLKS; k += NTHR) m = fmaxf(m, partm[k]);
    m = wave_max(m);
    if (lane == 0) ms[w] = m;
    __syncthreads();
    const float M = fmaxf(fmaxf(ms[0], ms[1]), fmaxf(ms[2], ms[3]));
    float s = 0.f;
    for (int k = t; k < D3_BLKS; k += NTHR) s += parts[k] * expf(partm[k] - M);
    s = wave_sum(s);
    if (lane == 0) ss[w] = s;
    __syncthreads();
    const float L = logf(ss[0] + ss[1] + ss[2] + ss[3]);
    const int g = blockIdx.x * NTHR + t;  // 125*256 = 32000
    out[g] = out[g] - M - L;
}

extern "C" void kernel_launch(void* const* d_in, const int* in_sizes, int n_in,
                              void* d_out, int out_size, void* d_ws, size_t ws_size,
                              hipStream_t stream) {
    const int*   word = (const int*)d_in[0];
    const float* hin  = (const float*)d_in[1];
    const float* enc  = (const float*)d_in[2];
    const float* emb  = (const float*)d_in[3];
    // d_in[4] attn_W, d_in[5] attn_b: dead (softmax over size-1 axis)
    const float* Wih  = (const float*)d_in[6];
    const float* Whh  = (const float*)d_in[7];
    const float* bih  = (const float*)d_in[8];
    const float* bhh  = (const float*)d_in[9];
    const float* Wout = (const float*)d_in[10];
    const float* bout = (const float*)d_in[11];
    float* out = (float*)d_out;
    float* ws  = (float*)d_ws;

    float* colsum = ws;                  // [1024]
    float* gi     = colsum + H;          // [3072]
    float* gi2    = gi + 3 * H;          // [3072]
    float* gh     = gi2 + 3 * H;         // [3072]
    float* partm  = gh + 3 * H;          // [1000]
    float* parts  = partm + D3_BLKS;     // [1000]

    hipMemsetAsync(colsum, 0, H * sizeof(float), stream);
    k_front<<<D1_BLKS, NTHR, 0, stream>>>(enc, Whh, Wih, bih, bhh, hin, emb, word,
                                          colsum, gi, gh, out);
    k_gi2<<<D2_BLKS, NTHR, 0, stream>>>(Wih, colsum, gi2);
    k_logits<<<D3_BLKS, NTHR, 0, stream>>>(gi, gi2, gh, hin, Wout, bout, out,
                                           partm, parts);
    k_final<<<D4_BLKS, NTHR, 0, stream>>>(partm, parts, out);
}

// Round 12
// 47.340 us; speedup vs baseline: 1.5166x; 1.2519x over previous
//
#include <hip/hip_runtime.h>

// BahdanauAttnDecoderRNN single-step decode, MI355X — 4 stream-ordered kernels.
// Reference dead code: softmax over size-1 axis => attn_weights == 1.0;
// attn_W/attn_b/scores dead; attn_applied = colsum(encoder_outputs).
// Live work ~178 MB f32 reads (Wout 131 MB dominant) => ~28 us HBM roofline.
// Measured lessons (11 rounds):
//   - NO intra-kernel polling / grid.sync (R4 441us, R5 486us, R8 420us+wrong).
//   - NO serial winner-reduce on critical path (R10 +24us).
//   - NO extra dispatch nodes: hipMemsetAsync node alone cost ~11us (R11).
//   - Logits stream: few blocks x long per-wave streams (R9: 1000x32 best;
//     R10's 500x64 regressed).
//   - Balance per-block stream lengths within a dispatch (colsum chunk size).
// Structure = R9 (best, 47.9us) with ONE change: colsum 32x64row -> 64x32row
// chunks (128KB blocks, halves D1's long pole); D2 reduces 64 partials.
//   D1: colsum partials (64 chunks) + gh + emb-half gi + attn ones
//   D2: per-block redundant partial-reduce (256KB, L3) + gi2
//   D3: gates redundant per block + 32-row logits (8/wave) + (m,s)
//   D4: fixed-order reduce of 1000 partials + in-place log-softmax

namespace {
constexpr int H = 1024;
constexpr int V = 32000;
constexpr int S = 2048;
constexpr int NTHR = 256;
constexpr int CS_BLKS = 64;             // colsum chunks (128 KB each, balanced)
constexpr int CS_ROWS = S / CS_BLKS;    // 32 rows per chunk
constexpr int GRU_BLKS = 768;           // 3072 rows / 4 per block
constexpr int D1_BLKS = CS_BLKS + GRU_BLKS + 1;  // 833
constexpr int D2_BLKS = 192;            // 16 gi2 rows each
constexpr int D3_BLKS = 1000;           // 32 logits rows each (8 per wave)
constexpr int RPW = 8;                  // rows per wave in D3
constexpr int D4_BLKS = V / NTHR;       // 125
}

__device__ __forceinline__ float wave_sum(float v) {
#pragma unroll
    for (int off = 32; off > 0; off >>= 1) v += __shfl_xor(v, off, 64);
    return v;
}
__device__ __forceinline__ float wave_max(float v) {
#pragma unroll
    for (int off = 32; off > 0; off >>= 1) v = fmaxf(v, __shfl_xor(v, off, 64));
    return v;
}
__device__ __forceinline__ float dot4(float4 a, float4 b) {
    return a.x * b.x + a.y * b.y + a.z * b.z + a.w * b.w;
}

// D1: colsum partials + gh & emb-half of gi + attn ones.
__global__ __launch_bounds__(NTHR) void k_front(
    const float* __restrict__ enc, const float* __restrict__ Whh,
    const float* __restrict__ Wih, const float* __restrict__ bih,
    const float* __restrict__ bhh, const float* __restrict__ hin,
    const float* __restrict__ emb, const int* __restrict__ word,
    float* __restrict__ part, float* __restrict__ gi, float* __restrict__ gh,
    float* __restrict__ out) {
    const int b = blockIdx.x, t = threadIdx.x;
    if (b < CS_BLKS) {
        // rows [b*32, b*32+32); thread t owns float4-column t
        const float4* e = (const float4*)enc + (size_t)b * CS_ROWS * (H / 4) + t;
        float4 acc = make_float4(0.f, 0.f, 0.f, 0.f);
#pragma unroll
        for (int r = 0; r < CS_ROWS; ++r) {
            float4 v = e[(size_t)r * (H / 4)];
            acc.x += v.x; acc.y += v.y; acc.z += v.z; acc.w += v.w;
        }
        ((float4*)part)[b * (H / 4) + t] = acc;
    } else if (b < CS_BLKS + GRU_BLKS) {
        const int lane = t & 63, w = t >> 6;
        const int row = (b - CS_BLKS) * 4 + w;  // < 3072
        const float4* wh = (const float4*)Whh + (size_t)row * (H / 4);
        const float4* xh = (const float4*)hin;
        const float4* wi = (const float4*)Wih + (size_t)row * (2 * H / 4);
        const float4* er = (const float4*)emb + (size_t)word[0] * (H / 4);
        float ah = 0.f, ai = 0.f;
#pragma unroll
        for (int it = 0; it < 4; ++it) {
            const int idx = it * 64 + lane;
            ah += dot4(wh[idx], xh[idx]);
            float4 e4 = er[idx];
            e4.x = fmaxf(e4.x, 0.f); e4.y = fmaxf(e4.y, 0.f);
            e4.z = fmaxf(e4.z, 0.f); e4.w = fmaxf(e4.w, 0.f);
            ai += dot4(wi[idx], e4);
        }
        ah = wave_sum(ah);
        ai = wave_sum(ai);
        if (lane == 0) {
            gh[row] = ah + bhh[row];
            gi[row] = ai + bih[row];  // colsum half lives in gi2
        }
    } else {
        // attn_weights are exactly 1.0 (softmax over size-1 axis)
#pragma unroll
        for (int k = 0; k < S / NTHR; ++k) out[V + H + k * NTHR + t] = 1.0f;
    }
}

// D2: per-block redundant reduce of 64 colsum partials -> relu -> LDS;
// then 16 rows of gi2 = Wih[:, H:2H] . rn.
__global__ __launch_bounds__(NTHR) void k_gi2(
    const float* __restrict__ Wih, const float* __restrict__ part,
    float* __restrict__ gi2) {
    __shared__ float4 rn[H / 4];
    const int t = threadIdx.x, lane = t & 63, w = t >> 6;
    float4 acc = make_float4(0.f, 0.f, 0.f, 0.f);
#pragma unroll 8
    for (int c = 0; c < CS_BLKS; ++c) {
        float4 v = ((const float4*)part)[c * (H / 4) + t];
        acc.x += v.x; acc.y += v.y; acc.z += v.z; acc.w += v.w;
    }
    acc.x = fmaxf(acc.x, 0.f); acc.y = fmaxf(acc.y, 0.f);
    acc.z = fmaxf(acc.z, 0.f); acc.w = fmaxf(acc.w, 0.f);
    rn[t] = acc;
    __syncthreads();
#pragma unroll
    for (int i = 0; i < 4; ++i) {
        const int row = blockIdx.x * 16 + w * 4 + i;  // < 3072
        const float4* wr = (const float4*)Wih + (size_t)row * (2 * H / 4) + (H / 4);
        float a = 0.f;
#pragma unroll
        for (int it = 0; it < 4; ++it) {
            const int idx = it * 64 + lane;
            a += dot4(wr[idx], rn[idx]);
        }
        a = wave_sum(a);
        if (lane == 0) gi2[row] = a;
    }
}

// D3: gates redundant per block -> h_new in LDS -> 32-row Wout matvec
// (8 rows/wave, register batch) -> raw logits + per-block (m,s) partial.
__global__ __launch_bounds__(NTHR) void k_logits(
    const float* __restrict__ gi, const float* __restrict__ gi2,
    const float* __restrict__ gh, const float* __restrict__ hin,
    const float* __restrict__ Wout, const float* __restrict__ bout,
    float* __restrict__ out, float* __restrict__ partm, float* __restrict__ parts) {
    __shared__ float hnew[H];
    __shared__ float bm[4], bs[4];
    const int t = threadIdx.x, lane = t & 63, w = t >> 6;
#pragma unroll
    for (int q = 0; q < 4; ++q) {
        const int j = q * NTHR + t;
        const float gr = gi[j] + gi2[j] + gh[j];
        const float gz = gi[H + j] + gi2[H + j] + gh[H + j];
        const float r = 1.f / (1.f + expf(-gr));
        const float z = 1.f / (1.f + expf(-gz));
        const float n = tanhf(gi[2 * H + j] + gi2[2 * H + j] + r * gh[2 * H + j]);
        const float hv = (1.f - z) * n + z * hin[j];
        hnew[j] = hv;
        if (blockIdx.x == 0) out[V + j] = hv;  // hidden-state output
    }
    __syncthreads();
    const float4* hn4 = (const float4*)hnew;
    const float4 x0 = hn4[lane], x1 = hn4[64 + lane];
    const float4 x2 = hn4[128 + lane], x3 = hn4[192 + lane];
    float a[RPW];
#pragma unroll 2
    for (int i = 0; i < RPW; ++i) {
        const int row = blockIdx.x * 32 + w * RPW + i;  // < 32000
        const float4* wr = (const float4*)Wout + (size_t)row * (H / 4);
        float v = dot4(wr[lane], x0) + dot4(wr[64 + lane], x1) +
                  dot4(wr[128 + lane], x2) + dot4(wr[192 + lane], x3);
        a[i] = wave_sum(v) + bout[row];  // identical on all lanes
        if (lane == 0) out[row] = a[i];  // raw logit
    }
    float m = a[0];
#pragma unroll
    for (int i = 1; i < RPW; ++i) m = fmaxf(m, a[i]);
    float s = 0.f;
#pragma unroll
    for (int i = 0; i < RPW; ++i) s += expf(a[i] - m);
    if (lane == 0) { bm[w] = m; bs[w] = s; }
    __syncthreads();
    if (t == 0) {
        const float M = fmaxf(fmaxf(bm[0], bm[1]), fmaxf(bm[2], bm[3]));
        const float ss = bs[0] * expf(bm[0] - M) + bs[1] * expf(bm[1] - M) +
                         bs[2] * expf(bm[2] - M) + bs[3] * expf(bm[3] - M);
        partm[blockIdx.x] = M;
        parts[blockIdx.x] = ss;
    }
}

// D4: redundant fixed-order reduce of 1000 partials + in-place log-softmax.
__global__ __launch_bounds__(NTHR) void k_final(
    const float* __restrict__ partm, const float* __restrict__ parts,
    float* __restrict__ out) {
    __shared__ float ms[4], ss[4];
    const int t = threadIdx.x, lane = t & 63, w = t >> 6;
    float m = -3.4e38f;
    for (int k = t; k < D3_BLKS; k += NTHR) m = fmaxf(m, partm[k]);
    m = wave_max(m);
    if (lane == 0) ms[w] = m;
    __syncthreads();
    const float M = fmaxf(fmaxf(ms[0], ms[1]), fmaxf(ms[2], ms[3]));
    float s = 0.f;
    for (int k = t; k < D3_BLKS; k += NTHR) s += parts[k] * expf(partm[k] - M);
    s = wave_sum(s);
    if (lane == 0) ss[w] = s;
    __syncthreads();
    const float L = logf(ss[0] + ss[1] + ss[2] + ss[3]);
    const int g = blockIdx.x * NTHR + t;  // 125*256 = 32000
    out[g] = out[g] - M - L;
}

extern "C" void kernel_launch(void* const* d_in, const int* in_sizes, int n_in,
                              void* d_out, int out_size, void* d_ws, size_t ws_size,
                              hipStream_t stream) {
    const int*   word = (const int*)d_in[0];
    const float* hin  = (const float*)d_in[1];
    const float* enc  = (const float*)d_in[2];
    const float* emb  = (const float*)d_in[3];
    // d_in[4] attn_W, d_in[5] attn_b: dead (softmax over size-1 axis)
    const float* Wih  = (const float*)d_in[6];
    const float* Whh  = (const float*)d_in[7];
    const float* bih  = (const float*)d_in[8];
    const float* bhh  = (const float*)d_in[9];
    const float* Wout = (const float*)d_in[10];
    const float* bout = (const float*)d_in[11];
    float* out = (float*)d_out;
    float* ws  = (float*)d_ws;

    float* part  = ws;                  // [64*1024]
    float* gi    = part + CS_BLKS * H;  // [3072]
    float* gi2   = gi + 3 * H;          // [3072]
    float* gh    = gi2 + 3 * H;         // [3072]
    float* partm = gh + 3 * H;          // [1000]
    float* parts = partm + D3_BLKS;     // [1000]

    k_front<<<D1_BLKS, NTHR, 0, stream>>>(enc, Whh, Wih, bih, bhh, hin, emb, word,
                                          part, gi, gh, out);
    k_gi2<<<D2_BLKS, NTHR, 0, stream>>>(Wih, part, gi2);
    k_logits<<<D3_BLKS, NTHR, 0, stream>>>(gi, gi2, gh, hin, Wout, bout, out,
                                           partm, parts);
    k_final<<<D4_BLKS, NTHR, 0, stream>>>(partm, parts, out);
}